// Round 12
// baseline (59.224 us; speedup 1.0000x reference)
//
#include <hip/hip_runtime.h>
#include <hip/hip_bf16.h>

typedef unsigned short u16;
typedef __bf16 bf16x8 __attribute__((ext_vector_type(8)));
typedef float f32x4 __attribute__((ext_vector_type(4)));
typedef float f32x16 __attribute__((ext_vector_type(16)));
typedef unsigned short ushort8 __attribute__((ext_vector_type(8)));

#define C_IN   128
#define C_OUT  256
#define BATCH  16
#define LEN    4096
#define KS     9
#define PAD    4
#define LPAD   (LEN + 2*PAD)      // 4104
#define KTOT   (C_IN * KS)        // 1152
#define NSTEP  72                 // K = 1152 / 16

#define XT_BLKS    1040           // 65 * 16
#define W5_BLKS    1152           // 294912 / 256
#define EB_BLKS    256

__device__ inline u16 f2bf(float f) {
    __hip_bfloat16 h = __float2bfloat16(f);
    return __builtin_bit_cast(u16, h);
}

// async global->LDS, 16B per lane, wave-uniform LDS base + lane*16
__device__ __forceinline__ void g2l16(const void* g, void* l) {
    __builtin_amdgcn_global_load_lds(
        (const __attribute__((address_space(1))) void*)g,
        (__attribute__((address_space(3))) void*)l, 16, 0, 0);
}

// ---------------------------------------------------------------------------
// Fused prep (one launch) — UNCHANGED (verified absmax 0.03125 since R9):
//  blocks [0,1040): x [B][C][L] f32 -> xt [B][LPAD][C] bf16, edge-padded,
//    4-bit XOR swizzle (16B-block idx ^= l&15) baked into global layout.
//  blocks [1040,2192): weight -> w5 in 32-lane fragment order for
//    mfma_f32_32x32x16_bf16:  i = ((s*8 + g)*64 + lane)*8 + e  where
//    o = g*32 + (lane&31), hi = lane>>5, c = (s&7)*16 + hi*8 + e, k = s>>3.
//  blocks [2192,2448): ebias[o] = bias[o] + sum offset*W; block 2192: phys.
// ---------------------------------------------------------------------------
__global__ void prep_all(const float* __restrict__ x, const float* __restrict__ w,
                         const float* __restrict__ bias, const float* __restrict__ vel,
                         const float* __restrict__ acc_in,
                         u16* __restrict__ xt, u16* __restrict__ w5,
                         float* __restrict__ ebias, float* __restrict__ phys_out) {
    int bid = blockIdx.x;
    int t = threadIdx.x;
    if (bid < XT_BLKS) {
        int b    = bid / 65;
        int lblk = bid % 65;
        int lane = t & 63;
        int jb   = t >> 6;
        int lp   = lblk * 64 + lane;
        if (lp >= LPAD) return;
        int l = lp - PAD;
        l = l < 0 ? 0 : (l > LEN - 1 ? LEN - 1 : l);
        const float* xb = x + (size_t)b * C_IN * LEN + l;
        u16* row = xt + ((size_t)b * LPAD + lp) * C_IN;
        int key = lp & 15;
        #pragma unroll
        for (int jj = 0; jj < 4; ++jj) {
            int cblk = jb * 4 + jj;
            ushort8 v;
            #pragma unroll
            for (int e = 0; e < 8; ++e)
                v[e] = f2bf(xb[(size_t)(cblk * 8 + e) * LEN]);
            int jstore = cblk ^ key;
            *reinterpret_cast<ushort8*>(row + jstore * 8) = v;
        }
        return;
    }
    if (bid < XT_BLKS + W5_BLKS) {
        int i = (bid - XT_BLKS) * 256 + t;   // 294912 total
        int e    = i & 7;
        int lane = (i >> 3) & 63;
        int g    = (i >> 9) & 7;
        int s    = i >> 12;                  // 0..71
        int o    = g * 32 + (lane & 31);
        int hi   = lane >> 5;
        int c    = (s & 7) * 16 + hi * 8 + e;
        int k    = s >> 3;
        w5[i] = f2bf(w[((size_t)o * C_IN + c) * KS + k]);
        return;
    }
    __shared__ float red[256];
    int o = bid - (XT_BLKS + W5_BLKS);
    float sum = 0.f;
    for (int i = t; i < KTOT; i += 256) {
        int k = i % KS;                    // offset layout [c][k]
        float tk = k * 0.01f;              // DT
        float off = vel[i] * tk + 0.5f * acc_in[i] * tk * tk;
        sum += off * w[(size_t)o * KTOT + i];
    }
    red[t] = sum;
    __syncthreads();
    for (int h = 128; h > 0; h >>= 1) {
        if (t < h) red[t] += red[t + h];
        __syncthreads();
    }
    if (t == 0) ebias[o] = bias[o] + red[0];

    if (o == 0) {                          // phys
        __syncthreads();
        float pv = 0.f;
        for (int i = t; i < KTOT; i += 256) {
            float v = vel[i], a = acc_in[i];
            pv += v * v + a * a;
        }
        red[t] = pv;
        __syncthreads();
        for (int h = 128; h > 0; h >>= 1) {
            if (t < h) red[t] += red[t + h];
            __syncthreads();
        }
        if (t == 0) *phys_out = 0.01f * (red[0] / (float)KTOT);
    }
}

// ---------------------------------------------------------------------------
// Main: R11 fat-wave barrier-free base + two fixes for the L2-write-thrash
// theory (5 schedules all pinned at ~41.5us; MfmaUtil ~34% universal; the
// 65MB output stream evicts w5/xt from the 4MB per-XCD L2 -> A-loads served
// at L3 latency ~500-900cyc > every schedule's prefetch distance):
//  FIX 1: __builtin_nontemporal_store on the epilogue -> writes bypass L2.
//  FIX 2: A/B prefetch distance 2 (triple-buffered regs, ~1100cyc cover).
// Wave tile 128o x 128l (acc 256 regs, 1 wave/SIMD at 512-reg budget).
// Block = 2 waves = 256o x 128l; grid 512 = 2 blocks/CU.
// ---------------------------------------------------------------------------
__global__ __launch_bounds__(128, 1) void conv_main(const u16* __restrict__ xt,
                                                    const u16* __restrict__ w5,
                                                    const float* __restrict__ ebias,
                                                    float* __restrict__ out) {
    __shared__ u16 ldsx[17408];            // B tile: 136 rows x 256B = 34816 B

    int b     = blockIdx.y;
    int lbase = blockIdx.x * 128;
    int t     = threadIdx.x;               // 0..127
    int lane  = t & 63;
    int wm    = t >> 6;                    // wave = o-half (128 o each)
    int l31   = lane & 31;
    int hi    = lane >> 5;

    // A source: wave wm's 4 o-groups (g = wm*4+mi) -> contiguous 4KB/step
    const u16* alane = w5 + ((size_t)(wm * 4) * 64 + lane) * 8;

    #define LOAD_A(S, AF)                                                        \
        {                                                                        \
            const u16* p_ = alane + (size_t)(S) * 4096;                          \
            _Pragma("unroll")                                                    \
            for (int mi = 0; mi < 4; ++mi)                                       \
                AF[mi] = *reinterpret_cast<const bf16x8*>(p_ + mi * 512);        \
        }
    #define LOAD_B(S, BF)                                                        \
        {                                                                        \
            int k_ = (S) >> 3;                                                   \
            int sl_ = ((S) & 7) * 2 + hi;                                        \
            _Pragma("unroll")                                                    \
            for (int nj = 0; nj < 4; ++nj) {                                     \
                int row_  = nj * 32 + l31 + k_;                                  \
                int addr_ = row_ * 256 + ((sl_ ^ (row_ & 15)) << 4);             \
                BF[nj] = *reinterpret_cast<const bf16x8*>(ldsbase + addr_);      \
            }                                                                    \
        }
    #define MFMA16(AF, BF)                                                       \
        {                                                                        \
            _Pragma("unroll")                                                    \
            for (int mi = 0; mi < 4; ++mi)                                       \
                _Pragma("unroll")                                                \
                for (int nj = 0; nj < 4; ++nj)                                   \
                    acc[mi][nj] = __builtin_amdgcn_mfma_f32_32x32x16_bf16(       \
                        AF[mi], BF[nj], acc[mi][nj], 0, 0, 0);                   \
        }

    bf16x8 aA[4], aB[4], aC[4], bA[4], bB[4], bC[4];

    // ---- prologue: stage B tile (2176 16B-units, 17 calls x 128 threads)
    {
        const u16* bsrc = xt + ((size_t)b * LPAD + lbase) * C_IN;
        #pragma unroll
        for (int j = 0; j < 17; ++j)
            g2l16(bsrc + (j * 128 + t) * 8, ldsx + (j * 128 + wm * 64) * 8);
    }
    LOAD_A(0, aA);                         // independent of LDS; issue early
    __syncthreads();                       // drains staging; the only barrier

    f32x16 acc[4][4] = {};
    const char* ldsbase = reinterpret_cast<const char*>(ldsx);
    LOAD_B(0, bA);
    LOAD_A(1, aB); LOAD_B(1, bB);          // fill pipeline to distance 2

    #pragma unroll
    for (int s = 0; s < NSTEP; s += 3) {   // 72 = 3 * 24, exact
        if (s + 2 < NSTEP) { LOAD_A(s + 2, aC); LOAD_B(s + 2, bC); }
        MFMA16(aA, bA);
        if (s + 3 < NSTEP) { LOAD_A(s + 3, aA); LOAD_B(s + 3, bA); }
        MFMA16(aB, bB);
        if (s + 4 < NSTEP) { LOAD_A(s + 4, aB); LOAD_B(s + 4, bB); }
        if (s + 2 < NSTEP) MFMA16(aC, bC);
    }

    // ---- epilogue: 32x32 D layout col = lane&31 (l), row = (reg&3)+8*(reg>>2)+4*hi
    // NONTEMPORAL stores: output is write-once, never re-read -> bypass L2
    // so the 65MB stream stops evicting w5/xt (the hypothesized 41.5us wall).
    #pragma unroll
    for (int mi = 0; mi < 4; ++mi) {
        int o0 = wm * 128 + mi * 32 + hi * 4;
        #pragma unroll
        for (int nj = 0; nj < 4; ++nj) {
            int l = lbase + nj * 32 + l31;
            #pragma unroll
            for (int q = 0; q < 4; ++q) {
                f32x4 eb = *reinterpret_cast<const f32x4*>(ebias + o0 + q * 8);
                float* op = out + (size_t)(b * C_OUT + o0 + q * 8) * LEN + l;
                #pragma unroll
                for (int p = 0; p < 4; ++p)
                    __builtin_nontemporal_store(acc[mi][nj][q * 4 + p] + eb[p],
                                                op + (size_t)p * LEN);
            }
        }
    }
    #undef LOAD_A
    #undef LOAD_B
    #undef MFMA16
}

extern "C" void kernel_launch(void* const* d_in, const int* in_sizes, int n_in,
                              void* d_out, int out_size, void* d_ws, size_t ws_size,
                              hipStream_t stream) {
    const float* x      = (const float*)d_in[0];
    const float* weight = (const float*)d_in[1];
    const float* bias   = (const float*)d_in[2];
    const float* vel    = (const float*)d_in[3];
    const float* acc    = (const float*)d_in[4];
    float* out = (float*)d_out;

    char* ws = (char*)d_ws;
    u16*  xt    = (u16*)ws;                                       // 16,797,696 B
    u16*  w5    = (u16*)(ws + (size_t)BATCH * LPAD * C_IN * 2);   // 589,824 B
    float* ebias = (float*)(ws + (size_t)BATCH * LPAD * C_IN * 2 + (size_t)C_OUT * KTOT * 2);

    hipLaunchKernelGGL(prep_all, dim3(XT_BLKS + W5_BLKS + EB_BLKS), dim3(256), 0, stream,
                       x, weight, bias, vel, acc, xt, w5, ebias,
                       out + (size_t)BATCH * C_OUT * LEN);
    hipLaunchKernelGGL(conv_main, dim3(LEN / 128, BATCH), dim3(128), 0, stream,
                       xt, w5, ebias, out);
}